// Round 1
// baseline (601.955 us; speedup 1.0000x reference)
//
#include <hip/hip_runtime.h>
#include <stdint.h>

typedef unsigned short u16;
typedef __attribute__((ext_vector_type(8))) short short8;
typedef __attribute__((ext_vector_type(4))) float f32x4;

#define MFMA16(a, b, c) __builtin_amdgcn_mfma_f32_16x16x32_bf16((a), (b), (c), 0, 0, 0)
#define LOG2E 1.4426950408889634f
#define SCALE 0.03125f  // 1/sqrt(1024)

__device__ __forceinline__ u16 f2bf(float f) {
  union { float f; uint32_t u; } cv; cv.f = f;
  uint32_t u = cv.u;
  uint32_t r = (u + 0x7fffu + ((u >> 16) & 1u)) >> 16;  // RTNE
  return (u16)r;
}

// ---------------- fp32 -> bf16 conversion ----------------
__global__ void cvt_kernel(const float* __restrict__ src, u16* __restrict__ dst, int n8) {
  int i = blockIdx.x * blockDim.x + threadIdx.x;
  int stride = gridDim.x * blockDim.x;
  for (; i < n8; i += stride) {
    const f32x4* s = (const f32x4*)src + (size_t)i * 2;
    f32x4 a = s[0], b = s[1];
    short8 o;
    o[0] = (short)f2bf(a[0]); o[1] = (short)f2bf(a[1]);
    o[2] = (short)f2bf(a[2]); o[3] = (short)f2bf(a[3]);
    o[4] = (short)f2bf(b[0]); o[5] = (short)f2bf(b[1]);
    o[6] = (short)f2bf(b[2]); o[7] = (short)f2bf(b[3]);
    *((short8*)dst + i) = o;
  }
}

// ---------------- QKV projection GEMM: C = A @ W^T + bias (bf16 out) ----------------
// A: [8192][1024] bf16, W: [1024][1024] bf16 (row-major, accessed as B^T), C: [8192][1024] bf16
// 128x128 tile, BK=32, 4 waves each computing 64x64 via 4x4 16x16x32 MFMA frags.
__device__ __forceinline__ int swz(int row, int c8) {
  // ushort-index into [128][32] tile, 16B-chunk XOR swizzle to spread banks
  return row * 32 + ((c8 ^ ((row >> 1) & 3)) << 3);
}

__global__ void gemm_qkv(const u16* __restrict__ xb,
                         const u16* __restrict__ wqb, const u16* __restrict__ wkb,
                         const u16* __restrict__ wvb,
                         const float* __restrict__ bq, const float* __restrict__ bk,
                         const float* __restrict__ bv,
                         u16* __restrict__ qo, u16* __restrict__ ko, u16* __restrict__ vo) {
  __shared__ __align__(16) u16 As[128 * 32];
  __shared__ __align__(16) u16 Bs[128 * 32];
  const int z = blockIdx.z;
  const u16* W = (z == 0) ? wqb : (z == 1) ? wkb : wvb;
  const float* bias = (z == 0) ? bq : (z == 1) ? bk : bv;
  u16* out = (z == 0) ? qo : (z == 1) ? ko : vo;
  const int n0 = blockIdx.x * 128;
  const int m0 = blockIdx.y * 128;
  const int t = threadIdx.x;
  const int lane = t & 63;
  const int w = t >> 6;
  const int l15 = lane & 15, l4 = lane >> 4;
  const int mw = (w >> 1) * 64, nw = (w & 1) * 64;

  const int srow = t >> 2, sc8 = t & 3;
  const u16* aG = xb + (size_t)(m0 + srow) * 1024 + sc8 * 8;
  const u16* bG = W + (size_t)(n0 + srow) * 1024 + sc8 * 8;

  float biasv[4];
#pragma unroll
  for (int nj = 0; nj < 4; nj++) biasv[nj] = bias[n0 + nw + nj * 16 + l15];

  const f32x4 fz = {0.f, 0.f, 0.f, 0.f};
  f32x4 acc[4][4];
#pragma unroll
  for (int i = 0; i < 4; i++)
#pragma unroll
    for (int j = 0; j < 4; j++) acc[i][j] = fz;

  const int wA0 = swz(srow, sc8), wA1 = swz(srow + 64, sc8);

  for (int k0 = 0; k0 < 1024; k0 += 32) {
    short8 a0 = *(const short8*)(aG + k0);
    short8 a1 = *(const short8*)(aG + k0 + 65536);
    short8 b0 = *(const short8*)(bG + k0);
    short8 b1 = *(const short8*)(bG + k0 + 65536);
    __syncthreads();  // previous iter's frag reads done before overwrite
    *(short8*)(As + wA0) = a0;
    *(short8*)(As + wA1) = a1;
    *(short8*)(Bs + wA0) = b0;
    *(short8*)(Bs + wA1) = b1;
    __syncthreads();
    short8 af[4], bf[4];
#pragma unroll
    for (int mi = 0; mi < 4; mi++) {
      int row = mw + mi * 16 + l15;
      af[mi] = *(const short8*)(As + swz(row, l4));
    }
#pragma unroll
    for (int nj = 0; nj < 4; nj++) {
      int row = nw + nj * 16 + l15;
      bf[nj] = *(const short8*)(Bs + swz(row, l4));
    }
#pragma unroll
    for (int mi = 0; mi < 4; mi++)
#pragma unroll
      for (int nj = 0; nj < 4; nj++)
        acc[mi][nj] = MFMA16(af[mi], bf[nj], acc[mi][nj]);
  }

#pragma unroll
  for (int mi = 0; mi < 4; mi++)
#pragma unroll
    for (int nj = 0; nj < 4; nj++)
#pragma unroll
      for (int r = 0; r < 4; r++) {
        int row = m0 + mw + mi * 16 + l4 * 4 + r;
        int col = n0 + nw + nj * 16 + l15;
        out[(size_t)row * 1024 + col] = f2bf(acc[mi][nj][r] + biasv[nj]);
      }
}

// ---------------- per-group transpose of V: [2048][64] -> [64][2048] ----------------
__global__ void transpose_v(const u16* __restrict__ v, u16* __restrict__ vt) {
  __shared__ u16 tile[64][72];  // +8 pad to break bank conflicts
  const int g = blockIdx.y, kv0 = blockIdx.x * 64;
  const size_t gb = (size_t)g * 131072;
  const int t = threadIdx.x;
  const int r = t >> 3, c = (t & 7) * 8;
  const u16* src = v + gb + (size_t)kv0 * 64;
#pragma unroll
  for (int rr = 0; rr < 2; rr++) {
    short8 d = *(const short8*)(src + (size_t)(r + rr * 32) * 64 + c);
#pragma unroll
    for (int j = 0; j < 8; j++) tile[r + rr * 32][c + j] = (u16)d[j];
  }
  __syncthreads();
  u16* dst = vt + gb + kv0;
#pragma unroll
  for (int rr = 0; rr < 2; rr++) {
    int h = r + rr * 32;
    short8 o;
#pragma unroll
    for (int j = 0; j < 8; j++) o[j] = (short)tile[c + j][h];
    *(short8*)(dst + (size_t)h * 2048 + c) = o;
  }
}

// ---------------- flash attention over 64 groups of (2048 x 64) ----------------
// grid (32 qtiles, 64 groups), 256 threads = 4 waves, 16 q-rows per wave, KV step 32.
__global__ void attn_kernel(const u16* __restrict__ q, const u16* __restrict__ k,
                            const u16* __restrict__ vt, float* __restrict__ out) {
  __shared__ __align__(16) u16 plds[4][16][32];
  const int g = blockIdx.y;
  const int q0 = blockIdx.x * 64;
  const int t = threadIdx.x, lane = t & 63, w = t >> 6;
  const int l15 = lane & 15, l4 = lane >> 4;
  const size_t gb = (size_t)g * 131072;
  const int qr = q0 + w * 16;

  // Q A-frags (rows l15, k-chunks 0/1)
  const u16* qp = q + gb + (size_t)(qr + l15) * 64 + l4 * 8;
  short8 qf0 = *(const short8*)(qp);
  short8 qf1 = *(const short8*)(qp + 32);
  const u16* kbase = k + gb + (size_t)l15 * 64 + l4 * 8;
  const u16* vbase = vt + gb + (size_t)l15 * 2048 + l4 * 8;
  u16(*pw)[32] = plds[w];

  const f32x4 fz = {0.f, 0.f, 0.f, 0.f};
  f32x4 o[4];
  float mrow[4], lrow[4];
#pragma unroll
  for (int r = 0; r < 4; r++) { mrow[r] = -1e30f; lrow[r] = 0.f; }
#pragma unroll
  for (int i = 0; i < 4; i++) o[i] = fz;

  for (int kv0 = 0; kv0 < 2048; kv0 += 32) {
    // S = Q K^T  (16 x 32), two 16-col blocks
    const u16* kp = kbase + (size_t)kv0 * 64;
    short8 kf00 = *(const short8*)(kp);
    short8 kf01 = *(const short8*)(kp + 32);
    short8 kf10 = *(const short8*)(kp + 1024);
    short8 kf11 = *(const short8*)(kp + 1024 + 32);
    f32x4 s0 = fz, s1 = fz;
    s0 = MFMA16(qf0, kf00, s0);
    s0 = MFMA16(qf1, kf01, s0);
    s1 = MFMA16(qf0, kf10, s1);
    s1 = MFMA16(qf1, kf11, s1);

    // online softmax; row r of D = q-row l4*4+r, cols spread over 16 lanes + 2 regs
    float p0[4], p1[4], alpha[4];
#pragma unroll
    for (int r = 0; r < 4; r++) {
      float cm = fmaxf(s0[r], s1[r]);
      cm = fmaxf(cm, __shfl_xor(cm, 1));
      cm = fmaxf(cm, __shfl_xor(cm, 2));
      cm = fmaxf(cm, __shfl_xor(cm, 4));
      cm = fmaxf(cm, __shfl_xor(cm, 8));
      float mn = fmaxf(mrow[r], cm * SCALE);
      alpha[r] = __builtin_amdgcn_exp2f((mrow[r] - mn) * LOG2E);
      mrow[r] = mn;
      p0[r] = __builtin_amdgcn_exp2f((s0[r] * SCALE - mn) * LOG2E);
      p1[r] = __builtin_amdgcn_exp2f((s1[r] * SCALE - mn) * LOG2E);
      float ps = p0[r] + p1[r];
      ps += __shfl_xor(ps, 1);
      ps += __shfl_xor(ps, 2);
      ps += __shfl_xor(ps, 4);
      ps += __shfl_xor(ps, 8);
      lrow[r] = lrow[r] * alpha[r] + ps;
    }
    // P (D-layout) -> LDS -> A-frag layout
#pragma unroll
    for (int r = 0; r < 4; r++) {
      pw[l4 * 4 + r][l15] = f2bf(p0[r]);
      pw[l4 * 4 + r][l15 + 16] = f2bf(p1[r]);
    }
    asm volatile("s_waitcnt lgkmcnt(0)" ::: "memory");  // within-wave LDS exchange
    short8 pa = *(const short8*)&pw[l15][l4 * 8];
    // rescale O then accumulate P @ V
#pragma unroll
    for (int nb = 0; nb < 4; nb++)
#pragma unroll
      for (int r = 0; r < 4; r++) o[nb][r] *= alpha[r];
    const u16* vp = vbase + kv0;
#pragma unroll
    for (int nb = 0; nb < 4; nb++) {
      short8 vf = *(const short8*)(vp + (size_t)nb * 16 * 2048);
      o[nb] = MFMA16(pa, vf, o[nb]);
    }
  }

  float inv[4];
#pragma unroll
  for (int r = 0; r < 4; r++) inv[r] = 1.f / lrow[r];
#pragma unroll
  for (int nb = 0; nb < 4; nb++)
#pragma unroll
    for (int r = 0; r < 4; r++)
      out[gb + (size_t)(qr + l4 * 4 + r) * 64 + nb * 16 + l15] = o[nb][r] * inv[r];
}

// ---------------- host launch ----------------
extern "C" void kernel_launch(void* const* d_in, const int* in_sizes, int n_in,
                              void* d_out, int out_size, void* d_ws, size_t ws_size,
                              hipStream_t stream) {
  const float* x  = (const float*)d_in[0];
  const float* Wq = (const float*)d_in[1];
  const float* bq = (const float*)d_in[2];
  const float* Wk = (const float*)d_in[3];
  const float* bk = (const float*)d_in[4];
  const float* Wv = (const float*)d_in[5];
  const float* bv = (const float*)d_in[6];
  float* out = (float*)d_out;

  const size_t NX = 8388608;   // 4*2048*1024
  const size_t NW = 1048576;   // 1024*1024
  u16* ws = (u16*)d_ws;
  u16* xb  = ws;                 // 8388608
  u16* wqb = xb + NX;            // 1048576
  u16* wkb = wqb + NW;
  u16* wvb = wkb + NW;
  u16* qb  = wvb + NW;           // 8388608
  u16* kb  = qb + NX;
  u16* vb  = kb + NX;
  u16* vtb = vb + NX;            // 8388608   (total ~90.2 MB)

  cvt_kernel<<<4096, 256, 0, stream>>>(x, xb, (int)(NX / 8));
  cvt_kernel<<<512, 256, 0, stream>>>(Wq, wqb, (int)(NW / 8));
  cvt_kernel<<<512, 256, 0, stream>>>(Wk, wkb, (int)(NW / 8));
  cvt_kernel<<<512, 256, 0, stream>>>(Wv, wvb, (int)(NW / 8));

  gemm_qkv<<<dim3(8, 64, 3), 256, 0, stream>>>(xb, wqb, wkb, wvb, bq, bk, bv, qb, kb, vb);

  transpose_v<<<dim3(32, 64), 256, 0, stream>>>(vb, vtb);

  attn_kernel<<<dim3(32, 64), 256, 0, stream>>>(qb, kb, vtb, out);
}

// Round 2
// 331.158 us; speedup vs baseline: 1.8177x; 1.8177x over previous
//
#include <hip/hip_runtime.h>
#include <stdint.h>

typedef unsigned short u16;
typedef __attribute__((ext_vector_type(8))) short short8;
typedef __attribute__((ext_vector_type(4))) float f32x4;
typedef __attribute__((ext_vector_type(16))) float f32x16;
typedef __attribute__((ext_vector_type(2))) unsigned int uv2;
typedef __attribute__((ext_vector_type(4))) unsigned int uv4;

#define MFMA16(a, b, c) __builtin_amdgcn_mfma_f32_16x16x32_bf16((a), (b), (c), 0, 0, 0)
#define MFMA32(a, b, c) __builtin_amdgcn_mfma_f32_32x32x16_bf16((a), (b), (c), 0, 0, 0)
#define LOG2E 1.4426950408889634f
#define SCALE 0.03125f  // 1/sqrt(1024)

__device__ __forceinline__ u16 f2bf(float f) {
  union { float f; uint32_t u; } cv; cv.f = f;
  uint32_t u = cv.u;
  uint32_t r = (u + 0x7fffu + ((u >> 16) & 1u)) >> 16;  // RTNE
  return (u16)r;
}

__device__ __forceinline__ unsigned cvtpk(float lo, float hi) {
  unsigned r;
  asm("v_cvt_pk_bf16_f32 %0, %1, %2" : "=v"(r) : "v"(lo), "v"(hi));
  return r;
}

// ---------------- fp32 -> bf16 conversion ----------------
__global__ void cvt_kernel(const float* __restrict__ src, u16* __restrict__ dst, int n8) {
  int i = blockIdx.x * blockDim.x + threadIdx.x;
  int stride = gridDim.x * blockDim.x;
  for (; i < n8; i += stride) {
    const f32x4* s = (const f32x4*)src + (size_t)i * 2;
    f32x4 a = s[0], b = s[1];
    short8 o;
    o[0] = (short)f2bf(a[0]); o[1] = (short)f2bf(a[1]);
    o[2] = (short)f2bf(a[2]); o[3] = (short)f2bf(a[3]);
    o[4] = (short)f2bf(b[0]); o[5] = (short)f2bf(b[1]);
    o[6] = (short)f2bf(b[2]); o[7] = (short)f2bf(b[3]);
    *((short8*)dst + i) = o;
  }
}

// ---------------- QKV projection GEMM: C = A @ W^T + bias (bf16 out) ----------------
__device__ __forceinline__ int swz(int row, int c8) {
  return row * 32 + ((c8 ^ ((row >> 1) & 3)) << 3);
}

__global__ void gemm_qkv(const u16* __restrict__ xb,
                         const u16* __restrict__ wqb, const u16* __restrict__ wkb,
                         const u16* __restrict__ wvb,
                         const float* __restrict__ bq, const float* __restrict__ bk,
                         const float* __restrict__ bv,
                         u16* __restrict__ qo, u16* __restrict__ ko, u16* __restrict__ vo) {
  __shared__ __align__(16) u16 As[128 * 32];
  __shared__ __align__(16) u16 Bs[128 * 32];
  const int z = blockIdx.z;
  const u16* W = (z == 0) ? wqb : (z == 1) ? wkb : wvb;
  const float* bias = (z == 0) ? bq : (z == 1) ? bk : bv;
  u16* out = (z == 0) ? qo : (z == 1) ? ko : vo;
  const int n0 = blockIdx.x * 128;
  const int m0 = blockIdx.y * 128;
  const int t = threadIdx.x;
  const int lane = t & 63;
  const int w = t >> 6;
  const int l15 = lane & 15, l4 = lane >> 4;
  const int mw = (w >> 1) * 64, nw = (w & 1) * 64;

  const int srow = t >> 2, sc8 = t & 3;
  const u16* aG = xb + (size_t)(m0 + srow) * 1024 + sc8 * 8;
  const u16* bG = W + (size_t)(n0 + srow) * 1024 + sc8 * 8;

  float biasv[4];
#pragma unroll
  for (int nj = 0; nj < 4; nj++) biasv[nj] = bias[n0 + nw + nj * 16 + l15];

  const f32x4 fz = {0.f, 0.f, 0.f, 0.f};
  f32x4 acc[4][4];
#pragma unroll
  for (int i = 0; i < 4; i++)
#pragma unroll
    for (int j = 0; j < 4; j++) acc[i][j] = fz;

  const int wA0 = swz(srow, sc8), wA1 = swz(srow + 64, sc8);

  for (int k0 = 0; k0 < 1024; k0 += 32) {
    short8 a0 = *(const short8*)(aG + k0);
    short8 a1 = *(const short8*)(aG + k0 + 65536);
    short8 b0 = *(const short8*)(bG + k0);
    short8 b1 = *(const short8*)(bG + k0 + 65536);
    __syncthreads();
    *(short8*)(As + wA0) = a0;
    *(short8*)(As + wA1) = a1;
    *(short8*)(Bs + wA0) = b0;
    *(short8*)(Bs + wA1) = b1;
    __syncthreads();
    short8 af[4], bf[4];
#pragma unroll
    for (int mi = 0; mi < 4; mi++) {
      int row = mw + mi * 16 + l15;
      af[mi] = *(const short8*)(As + swz(row, l4));
    }
#pragma unroll
    for (int nj = 0; nj < 4; nj++) {
      int row = nw + nj * 16 + l15;
      bf[nj] = *(const short8*)(Bs + swz(row, l4));
    }
#pragma unroll
    for (int mi = 0; mi < 4; mi++)
#pragma unroll
      for (int nj = 0; nj < 4; nj++)
        acc[mi][nj] = MFMA16(af[mi], bf[nj], acc[mi][nj]);
  }

#pragma unroll
  for (int mi = 0; mi < 4; mi++)
#pragma unroll
    for (int nj = 0; nj < 4; nj++)
#pragma unroll
      for (int r = 0; r < 4; r++) {
        int row = m0 + mw + mi * 16 + l4 * 4 + r;
        int col = n0 + nw + nj * 16 + l15;
        out[(size_t)row * 1024 + col] = f2bf(acc[mi][nj][r] + biasv[nj]);
      }
}

// ---------------- per-group transpose of V: [2048][64] -> [64][2048] ----------------
__global__ void transpose_v(const u16* __restrict__ v, u16* __restrict__ vt) {
  __shared__ u16 tile[64][72];
  const int g = blockIdx.y, kv0 = blockIdx.x * 64;
  const size_t gb = (size_t)g * 131072;
  const int t = threadIdx.x;
  const int r = t >> 3, c = (t & 7) * 8;
  const u16* src = v + gb + (size_t)kv0 * 64;
#pragma unroll
  for (int rr = 0; rr < 2; rr++) {
    short8 d = *(const short8*)(src + (size_t)(r + rr * 32) * 64 + c);
#pragma unroll
    for (int j = 0; j < 8; j++) tile[r + rr * 32][c + j] = (u16)d[j];
  }
  __syncthreads();
  u16* dst = vt + gb + kv0;
#pragma unroll
  for (int rr = 0; rr < 2; rr++) {
    int h = r + rr * 32;
    short8 o;
#pragma unroll
    for (int j = 0; j < 8; j++) o[j] = (short)tile[c + j][h];
    *(short8*)(dst + (size_t)h * 2048 + c) = o;
  }
}

// ---------------- flash attention, swapped-QK^T 32x32 structure ----------------
// 64 groups of (S=2048, hd=64). Block = 4 waves x 32 q-rows = 128 q-rows.
// Grid 1024 blocks, XCD-bijective swizzle so each XCD owns 8 groups (K/V L2-resident).
// Per wave, per KVBLK=64 step: 8 mfma32 QK^T + in-register softmax + 8 mfma32 PV.
__global__ __launch_bounds__(256, 2) void attn_kernel(const u16* __restrict__ q,
                                                      const u16* __restrict__ k,
                                                      const u16* __restrict__ vt,
                                                      float* __restrict__ out) {
  const int t = threadIdx.x, lane = t & 63, w = t >> 6;
  const int l31 = lane & 31, hi = lane >> 5;
  const int bid = blockIdx.x;
  const int nid = (bid & 7) * 128 + (bid >> 3);  // XCD-contiguous remap (1024 % 8 == 0)
  const int g = nid >> 4, qt = nid & 15;
  const size_t gb = (size_t)g * 131072;  // 2048*64
  const int q0 = qt * 128 + w * 32;

  // Q as B-operand of S^T = K·Q^T: lane holds Q[q0+l31][16ks + 8hi + j]
  const u16* qp = q + gb + (size_t)(q0 + l31) * 64 + hi * 8;
  short8 qf[4];
#pragma unroll
  for (int ks = 0; ks < 4; ks++) qf[ks] = *(const short8*)(qp + ks * 16);

  const u16* kp = k + gb + (size_t)l31 * 64 + hi * 8;
  const u16* vp0 = vt + gb + (size_t)l31 * 2048 + hi * 8;
  const u16* vp1 = vp0 + (size_t)32 * 2048;

  f32x16 o0, o1;
#pragma unroll
  for (int i = 0; i < 16; i++) { o0[i] = 0.f; o1[i] = 0.f; }
  float m = -1e30f, lsum = 0.f;

  for (int kv0 = 0; kv0 < 2048; kv0 += 64) {
    // K fragments: A-operand rows = kv, lane holds K[kv0+bb*32+l31][16ks+8hi+j]
    short8 kf0[4], kf1[4];
    const u16* kb0 = kp + (size_t)kv0 * 64;
#pragma unroll
    for (int ks = 0; ks < 4; ks++) {
      kf0[ks] = *(const short8*)(kb0 + ks * 16);
      kf1[ks] = *(const short8*)(kb0 + 2048 + ks * 16);  // +32 rows * 64
    }
    f32x16 s0, s1;
#pragma unroll
    for (int i = 0; i < 16; i++) { s0[i] = 0.f; s1[i] = 0.f; }
#pragma unroll
    for (int ks = 0; ks < 4; ks++) s0 = MFMA32(kf0[ks], qf[ks], s0);
#pragma unroll
    for (int ks = 0; ks < 4; ks++) s1 = MFMA32(kf1[ks], qf[ks], s1);

    // ---- in-register online softmax (lane pair (l, l+32) owns q-row l31) ----
    float cm = fmaxf(s0[0], s1[0]);
#pragma unroll
    for (int i = 1; i < 16; i++) cm = fmaxf(cm, fmaxf(s0[i], s1[i]));
    cm = fmaxf(cm, __shfl_xor(cm, 32));
    cm *= SCALE;
    if (!__all(cm - m <= 8.0f)) {  // defer-max: rescale only on real max growth
      float mnew = fmaxf(m, cm);
      float alpha = __builtin_amdgcn_exp2f((m - mnew) * LOG2E);
      lsum *= alpha;
#pragma unroll
      for (int r = 0; r < 16; r++) {
        float ar = __shfl(alpha, (r & 3) + 8 * (r >> 2) + 4 * hi);
        o0[r] *= ar; o1[r] *= ar;
      }
      m = mnew;
    }
    const float kc = SCALE * LOG2E;
    const float ml = m * LOG2E;
    f32x16 p0, p1;
    float ps = 0.f;
#pragma unroll
    for (int i = 0; i < 16; i++) {
      p0[i] = __builtin_amdgcn_exp2f(s0[i] * kc - ml);
      p1[i] = __builtin_amdgcn_exp2f(s1[i] * kc - ml);
      ps += p0[i] + p1[i];
    }
    lsum += ps;

    // ---- P (D-layout) -> A-frag via cvt_pk + permlane32_swap (no LDS) ----
    short8 pa[4];
#pragma unroll
    for (int ks = 0; ks < 4; ks++) {
      const f32x16& src = (ks < 2) ? p0 : p1;
      const int s = (ks & 1) * 8;
      unsigned a0 = cvtpk(src[s + 0], src[s + 1]);
      unsigned a1 = cvtpk(src[s + 2], src[s + 3]);
      unsigned b0 = cvtpk(src[s + 4], src[s + 5]);
      unsigned b1 = cvtpk(src[s + 6], src[s + 7]);
      uv2 r0 = __builtin_amdgcn_permlane32_swap(a0, b0, false, false);
      uv2 r1 = __builtin_amdgcn_permlane32_swap(a1, b1, false, false);
      union { uv4 u; short8 s8; } cc;
      cc.u[0] = r0[0]; cc.u[1] = r1[0]; cc.u[2] = r0[1]; cc.u[3] = r1[1];
      pa[ks] = cc.s8;
    }

    // ---- PV: O[q][d] += P·V, B-operand from V^T rows (contiguous 16B) ----
#pragma unroll
    for (int ks = 0; ks < 4; ks++) {
      short8 vf0 = *(const short8*)(vp0 + kv0 + ks * 16);
      short8 vf1 = *(const short8*)(vp1 + kv0 + ks * 16);
      o0 = MFMA32(pa[ks], vf0, o0);
      o1 = MFMA32(pa[ks], vf1, o1);
    }
  }

  float ltot = lsum + __shfl_xor(lsum, 32);
  float invl = 1.0f / ltot;
  float* ob = out + gb + (size_t)q0 * 64;
#pragma unroll
  for (int r = 0; r < 16; r++) {
    int qr = (r & 3) + 8 * (r >> 2) + 4 * hi;
    float ir = __shfl(invl, qr);
    ob[(size_t)qr * 64 + l31] = o0[r] * ir;
    ob[(size_t)qr * 64 + 32 + l31] = o1[r] * ir;
  }
}

// ---------------- host launch ----------------
extern "C" void kernel_launch(void* const* d_in, const int* in_sizes, int n_in,
                              void* d_out, int out_size, void* d_ws, size_t ws_size,
                              hipStream_t stream) {
  const float* x  = (const float*)d_in[0];
  const float* Wq = (const float*)d_in[1];
  const float* bq = (const float*)d_in[2];
  const float* Wk = (const float*)d_in[3];
  const float* bk = (const float*)d_in[4];
  const float* Wv = (const float*)d_in[5];
  const float* bv = (const float*)d_in[6];
  float* out = (float*)d_out;

  const size_t NX = 8388608;   // 4*2048*1024
  const size_t NW = 1048576;   // 1024*1024
  u16* ws = (u16*)d_ws;
  u16* xb  = ws;
  u16* wqb = xb + NX;
  u16* wkb = wqb + NW;
  u16* wvb = wkb + NW;
  u16* qb  = wvb + NW;
  u16* kb  = qb + NX;
  u16* vb  = kb + NX;
  u16* vtb = vb + NX;

  cvt_kernel<<<4096, 256, 0, stream>>>(x, xb, (int)(NX / 8));
  cvt_kernel<<<512, 256, 0, stream>>>(Wq, wqb, (int)(NW / 8));
  cvt_kernel<<<512, 256, 0, stream>>>(Wk, wkb, (int)(NW / 8));
  cvt_kernel<<<512, 256, 0, stream>>>(Wv, wvb, (int)(NW / 8));

  gemm_qkv<<<dim3(8, 64, 3), 256, 0, stream>>>(xb, wqb, wkb, wvb, bq, bk, bv, qb, kb, vb);

  transpose_v<<<dim3(32, 64), 256, 0, stream>>>(vb, vtb);

  attn_kernel<<<1024, 256, 0, stream>>>(qb, kb, vtb, out);
}

// Round 3
// 199.539 us; speedup vs baseline: 3.0167x; 1.6596x over previous
//
#include <hip/hip_runtime.h>
#include <stdint.h>

typedef unsigned short u16;
typedef __attribute__((ext_vector_type(8))) short short8;
typedef __attribute__((ext_vector_type(4))) float f32x4;
typedef __attribute__((ext_vector_type(16))) float f32x16;
typedef __attribute__((ext_vector_type(2))) unsigned int uv2;
typedef __attribute__((ext_vector_type(4))) unsigned int uv4;

#define MFMA16(a, b, c) __builtin_amdgcn_mfma_f32_16x16x32_bf16((a), (b), (c), 0, 0, 0)
#define MFMA32(a, b, c) __builtin_amdgcn_mfma_f32_32x32x16_bf16((a), (b), (c), 0, 0, 0)
#define LOG2E 1.4426950408889634f
#define SCALE 0.03125f  // 1/sqrt(1024)

__device__ __forceinline__ u16 f2bf(float f) {
  union { float f; uint32_t u; } cv; cv.f = f;
  uint32_t u = cv.u;
  uint32_t r = (u + 0x7fffu + ((u >> 16) & 1u)) >> 16;  // RTNE
  return (u16)r;
}

__device__ __forceinline__ unsigned cvtpk(float lo, float hi) {
  unsigned r;
  asm("v_cvt_pk_bf16_f32 %0, %1, %2" : "=v"(r) : "v"(lo), "v"(hi));
  return r;
}

__device__ __forceinline__ float m3(float a, float b, float c) {
  return fmaxf(fmaxf(a, b), c);
}

// ---------------- fp32 -> bf16 conversion ----------------
__global__ void cvt_kernel(const float* __restrict__ src, u16* __restrict__ dst, int n8) {
  int i = blockIdx.x * blockDim.x + threadIdx.x;
  int stride = gridDim.x * blockDim.x;
  for (; i < n8; i += stride) {
    const f32x4* s = (const f32x4*)src + (size_t)i * 2;
    f32x4 a = s[0], b = s[1];
    short8 o;
    o[0] = (short)f2bf(a[0]); o[1] = (short)f2bf(a[1]);
    o[2] = (short)f2bf(a[2]); o[3] = (short)f2bf(a[3]);
    o[4] = (short)f2bf(b[0]); o[5] = (short)f2bf(b[1]);
    o[6] = (short)f2bf(b[2]); o[7] = (short)f2bf(b[3]);
    *((short8*)dst + i) = o;
  }
}

// ---------------- QKV projection GEMM with fragment-packed epilogue ----------------
// Computes C = x @ W^T + bias, then stores each element directly into the MFMA
// fragment-packed layout the attention kernel consumes (1KB per 32x16 fragment,
// lane-contiguous). z=0/1 (Q,K): A/B-frag layout over (kv-rows, d). z=2 (V):
// PV-B-frag layout over (d-halves, kv).
__device__ __forceinline__ int swz(int row, int c8) {
  return row * 32 + ((c8 ^ ((row >> 1) & 3)) << 3);
}

__global__ void gemm_qkv(const u16* __restrict__ xb,
                         const u16* __restrict__ wqb, const u16* __restrict__ wkb,
                         const u16* __restrict__ wvb,
                         const float* __restrict__ bq, const float* __restrict__ bk,
                         const float* __restrict__ bv,
                         u16* __restrict__ qo, u16* __restrict__ ko, u16* __restrict__ vo) {
  __shared__ __align__(16) u16 As[128 * 32];
  __shared__ __align__(16) u16 Bs[128 * 32];
  const int z = blockIdx.z;
  const u16* W = (z == 0) ? wqb : (z == 1) ? wkb : wvb;
  const float* bias = (z == 0) ? bq : (z == 1) ? bk : bv;
  u16* out = (z == 0) ? qo : (z == 1) ? ko : vo;
  const int n0 = blockIdx.x * 128;
  const int m0 = blockIdx.y * 128;
  const int t = threadIdx.x;
  const int lane = t & 63;
  const int w = t >> 6;
  const int l15 = lane & 15, l4 = lane >> 4;
  const int mw = (w >> 1) * 64, nw = (w & 1) * 64;

  const int srow = t >> 2, sc8 = t & 3;
  const u16* aG = xb + (size_t)(m0 + srow) * 1024 + sc8 * 8;
  const u16* bG = W + (size_t)(n0 + srow) * 1024 + sc8 * 8;

  float biasv[4];
#pragma unroll
  for (int nj = 0; nj < 4; nj++) biasv[nj] = bias[n0 + nw + nj * 16 + l15];

  const f32x4 fz = {0.f, 0.f, 0.f, 0.f};
  f32x4 acc[4][4];
#pragma unroll
  for (int i = 0; i < 4; i++)
#pragma unroll
    for (int j = 0; j < 4; j++) acc[i][j] = fz;

  const int wA0 = swz(srow, sc8), wA1 = swz(srow + 64, sc8);

  for (int k0 = 0; k0 < 1024; k0 += 32) {
    short8 a0 = *(const short8*)(aG + k0);
    short8 a1 = *(const short8*)(aG + k0 + 65536);
    short8 b0 = *(const short8*)(bG + k0);
    short8 b1 = *(const short8*)(bG + k0 + 65536);
    __syncthreads();
    *(short8*)(As + wA0) = a0;
    *(short8*)(As + wA1) = a1;
    *(short8*)(Bs + wA0) = b0;
    *(short8*)(Bs + wA1) = b1;
    __syncthreads();
    short8 af[4], bf[4];
#pragma unroll
    for (int mi = 0; mi < 4; mi++) {
      int row = mw + mi * 16 + l15;
      af[mi] = *(const short8*)(As + swz(row, l4));
    }
#pragma unroll
    for (int nj = 0; nj < 4; nj++) {
      int row = nw + nj * 16 + l15;
      bf[nj] = *(const short8*)(Bs + swz(row, l4));
    }
#pragma unroll
    for (int mi = 0; mi < 4; mi++)
#pragma unroll
      for (int nj = 0; nj < 4; nj++)
        acc[mi][nj] = MFMA16(af[mi], bf[nj], acc[mi][nj]);
  }

  // ---- packed-fragment epilogue ----
  // flat idx = row*1024+col -> g = row>>7, rr = ((row&127)<<4)+(col>>6), d = col&63
#pragma unroll
  for (int mi = 0; mi < 4; mi++)
#pragma unroll
    for (int nj = 0; nj < 4; nj++) {
      const int col = n0 + nw + nj * 16 + l15;
      const int d = col & 63;
      const int colhi = col >> 6;
#pragma unroll
      for (int r = 0; r < 4; r++) {
        const int row = m0 + mw + mi * 16 + l4 * 4 + r;
        const int g = row >> 7;
        const int rr = ((row & 127) << 4) + colhi;
        const u16 val = f2bf(acc[mi][nj][r] + biasv[nj]);
        size_t off;
        if (z == 2) {
          // V: frag = (rr>>6)*8 + (d>>5)*4 + ((rr>>4)&3); lane = ((rr>>3)&1)*32 + (d&31); j = rr&7
          off = ((size_t)g << 17) +
                ((size_t)(((rr >> 6) << 3) + (((d >> 5)) << 2) + ((rr >> 4) & 3)) << 9) +
                ((((rr >> 3) & 1) << 5) + (d & 31)) * 8 + (rr & 7);
        } else {
          // Q/K: frag = (rr>>5)*4 + (d>>4); lane = ((d>>3)&1)*32 + (rr&31); j = d&7
          off = ((size_t)g << 17) +
                ((size_t)(((rr >> 5) << 2) + (d >> 4)) << 9) +
                ((((d >> 3) & 1) << 5) + (rr & 31)) * 8 + (d & 7);
        }
        out[off] = val;
      }
    }
}

// ---------------- flash attention, packed fragments, 64 q-rows/wave ----------------
// 64 groups x (S=2048, hd=64). Block = 4 waves x 64 q-rows = 256 q-rows.
// Grid 512 blocks (XCD-bijective remap). KV step 32, 2-deep register double-buffer.
// All global loads are lane-contiguous 1KB fragment loads.

__device__ __forceinline__ void qblock(f32x16& s, float& m, float& lsum,
                                       f32x16& o0, f32x16& o1,
                                       const short8* vf, int hi) {
  // row max over this lane's 16 values, then across the lane pair
  float c0 = m3(s[0], s[1], s[2]);
  float c1 = m3(s[3], s[4], s[5]);
  float c2 = m3(s[6], s[7], s[8]);
  float c3 = m3(s[9], s[10], s[11]);
  float c4 = m3(s[12], s[13], s[14]);
  float cm = fmaxf(m3(m3(c0, c1, c2), c3, c4), s[15]);
  cm = fmaxf(cm, __shfl_xor(cm, 32));
  cm *= SCALE;
  if (!__all(cm - m <= 8.0f)) {  // defer-max (T13)
    float mnew = fmaxf(m, cm);
    float alpha = __builtin_amdgcn_exp2f((m - mnew) * LOG2E);
    lsum *= alpha;
#pragma unroll
    for (int r = 0; r < 16; r++) {
      float ar = __shfl(alpha, (r & 3) + 8 * (r >> 2) + 4 * hi);
      o0[r] *= ar; o1[r] *= ar;
    }
    m = mnew;
  }
  const float kc = SCALE * LOG2E;
  const float ml = m * LOG2E;
  float p[16];
  float ps = 0.f;
#pragma unroll
  for (int i = 0; i < 16; i++) {
    p[i] = __builtin_amdgcn_exp2f(s[i] * kc - ml);
    ps += p[i];
  }
  lsum += ps;

  // P (D-layout) -> A-frags via cvt_pk + permlane32_swap (T12)
  short8 pa0, pa1;
  {
    unsigned a0 = cvtpk(p[0], p[1]);
    unsigned a1 = cvtpk(p[2], p[3]);
    unsigned b0 = cvtpk(p[4], p[5]);
    unsigned b1 = cvtpk(p[6], p[7]);
    uv2 r0 = __builtin_amdgcn_permlane32_swap(a0, b0, false, false);
    uv2 r1 = __builtin_amdgcn_permlane32_swap(a1, b1, false, false);
    union { uv4 u; short8 s8; } cc;
    cc.u[0] = r0[0]; cc.u[1] = r1[0]; cc.u[2] = r0[1]; cc.u[3] = r1[1];
    pa0 = cc.s8;
  }
  {
    unsigned a0 = cvtpk(p[8], p[9]);
    unsigned a1 = cvtpk(p[10], p[11]);
    unsigned b0 = cvtpk(p[12], p[13]);
    unsigned b1 = cvtpk(p[14], p[15]);
    uv2 r0 = __builtin_amdgcn_permlane32_swap(a0, b0, false, false);
    uv2 r1 = __builtin_amdgcn_permlane32_swap(a1, b1, false, false);
    union { uv4 u; short8 s8; } cc;
    cc.u[0] = r0[0]; cc.u[1] = r1[0]; cc.u[2] = r0[1]; cc.u[3] = r1[1];
    pa1 = cc.s8;
  }
  __builtin_amdgcn_s_setprio(1);
  o0 = MFMA32(pa0, vf[0], o0);
  o0 = MFMA32(pa1, vf[1], o0);
  o1 = MFMA32(pa0, vf[2], o1);
  o1 = MFMA32(pa1, vf[3], o1);
  __builtin_amdgcn_s_setprio(0);
}

#define LOADKV(KF, VF, T) do {                                              \
    const u16* kp_ = kbase + ((size_t)(T) << 11);                           \
    KF[0] = *(const short8*)(kp_);                                          \
    KF[1] = *(const short8*)(kp_ + 512);                                    \
    KF[2] = *(const short8*)(kp_ + 1024);                                   \
    KF[3] = *(const short8*)(kp_ + 1536);                                   \
    const int kk_ = (T) * 2;                                                \
    const u16* vp_ = vbase + ((size_t)(((kk_ >> 2) << 3) + (kk_ & 3)) << 9);\
    VF[0] = *(const short8*)(vp_);                                          \
    VF[1] = *(const short8*)(vp_ + 512);                                    \
    VF[2] = *(const short8*)(vp_ + 2048);                                   \
    VF[3] = *(const short8*)(vp_ + 2560);                                   \
  } while (0)

#define QKBLOCK(KF, VF)                                                     \
  do {                                                                      \
    f32x16 sA, sB;                                                          \
    _Pragma("unroll") for (int i = 0; i < 16; i++) { sA[i] = 0.f; sB[i] = 0.f; } \
    __builtin_amdgcn_s_setprio(1);                                          \
    _Pragma("unroll") for (int ks = 0; ks < 4; ks++) sA = MFMA32(KF[ks], qfA[ks], sA); \
    _Pragma("unroll") for (int ks = 0; ks < 4; ks++) sB = MFMA32(KF[ks], qfB[ks], sB); \
    __builtin_amdgcn_s_setprio(0);                                          \
    qblock(sA, mA, lA, oA0, oA1, VF, hi);                                   \
    qblock(sB, mB, lB, oB0, oB1, VF, hi);                                   \
  } while (0)

__global__ __launch_bounds__(256, 2) void attn_kernel(const u16* __restrict__ Qp,
                                                      const u16* __restrict__ Kp,
                                                      const u16* __restrict__ Vp,
                                                      float* __restrict__ out) {
  const int t = threadIdx.x, lane = t & 63, w = t >> 6;
  const int l31 = lane & 31, hi = lane >> 5;
  const int bid = blockIdx.x;
  const int nid = (bid & 7) * 64 + (bid >> 3);  // XCD-contiguous remap (512 % 8 == 0)
  const int g = nid >> 3, qt = nid & 7;
  const size_t gb = (size_t)g * 131072;
  const int q0 = qt * 256 + w * 64;
  const int blkA = q0 >> 5;

  const u16* qbase = Qp + gb + (size_t)lane * 8;
  short8 qfA[4], qfB[4];
#pragma unroll
  for (int ks = 0; ks < 4; ks++) {
    qfA[ks] = *(const short8*)(qbase + ((size_t)(blkA * 4 + ks) << 9));
    qfB[ks] = *(const short8*)(qbase + ((size_t)((blkA + 1) * 4 + ks) << 9));
  }

  const u16* kbase = Kp + gb + (size_t)lane * 8;
  const u16* vbase = Vp + gb + (size_t)lane * 8;

  f32x16 oA0, oA1, oB0, oB1;
#pragma unroll
  for (int i = 0; i < 16; i++) { oA0[i] = 0.f; oA1[i] = 0.f; oB0[i] = 0.f; oB1[i] = 0.f; }
  float mA = -1e30f, lA = 0.f, mB = -1e30f, lB = 0.f;

  short8 kf0[4], kf1[4], vf0[4], vf1[4];
  LOADKV(kf0, vf0, 0);

  for (int tt = 0; tt < 64; tt += 2) {
    LOADKV(kf1, vf1, tt + 1);
    QKBLOCK(kf0, vf0);
    if (tt + 2 < 64) LOADKV(kf0, vf0, tt + 2);
    QKBLOCK(kf1, vf1);
  }

  float ltA = lA + __shfl_xor(lA, 32);
  float ltB = lB + __shfl_xor(lB, 32);
  float invA = 1.0f / ltA, invB = 1.0f / ltB;
  float* obA = out + gb + (size_t)q0 * 64;
  float* obB = obA + 32 * 64;
#pragma unroll
  for (int r = 0; r < 16; r++) {
    int qr = (r & 3) + 8 * (r >> 2) + 4 * hi;
    float irA = __shfl(invA, qr);
    float irB = __shfl(invB, qr);
    obA[(size_t)qr * 64 + l31] = oA0[r] * irA;
    obA[(size_t)qr * 64 + 32 + l31] = oA1[r] * irA;
    obB[(size_t)qr * 64 + l31] = oB0[r] * irB;
    obB[(size_t)qr * 64 + 32 + l31] = oB1[r] * irB;
  }
}

// ---------------- host launch ----------------
extern "C" void kernel_launch(void* const* d_in, const int* in_sizes, int n_in,
                              void* d_out, int out_size, void* d_ws, size_t ws_size,
                              hipStream_t stream) {
  const float* x  = (const float*)d_in[0];
  const float* Wq = (const float*)d_in[1];
  const float* bq = (const float*)d_in[2];
  const float* Wk = (const float*)d_in[3];
  const float* bk = (const float*)d_in[4];
  const float* Wv = (const float*)d_in[5];
  const float* bv = (const float*)d_in[6];
  float* out = (float*)d_out;

  const size_t NX = 8388608;   // 4*2048*1024
  const size_t NW = 1048576;   // 1024*1024
  u16* ws = (u16*)d_ws;
  u16* xb  = ws;
  u16* wqb = xb + NX;
  u16* wkb = wqb + NW;
  u16* wvb = wkb + NW;
  u16* qb  = wvb + NW;   // Q packed
  u16* kb  = qb + NX;    // K packed
  u16* vb  = kb + NX;    // V packed

  cvt_kernel<<<4096, 256, 0, stream>>>(x, xb, (int)(NX / 8));
  cvt_kernel<<<512, 256, 0, stream>>>(Wq, wqb, (int)(NW / 8));
  cvt_kernel<<<512, 256, 0, stream>>>(Wk, wkb, (int)(NW / 8));
  cvt_kernel<<<512, 256, 0, stream>>>(Wv, wvb, (int)(NW / 8));

  gemm_qkv<<<dim3(8, 64, 3), 256, 0, stream>>>(xb, wqb, wkb, wvb, bq, bk, bv, qb, kb, vb);

  attn_kernel<<<512, 256, 0, stream>>>(qb, kb, vb, out);
}

// Round 4
// 173.268 us; speedup vs baseline: 3.4741x; 1.1516x over previous
//
#include <hip/hip_runtime.h>
#include <stdint.h>

typedef unsigned short u16;
typedef __attribute__((ext_vector_type(8))) short short8;
typedef __attribute__((ext_vector_type(4))) float f32x4;
typedef __attribute__((ext_vector_type(16))) float f32x16;
typedef __attribute__((ext_vector_type(2))) unsigned int uv2;
typedef __attribute__((ext_vector_type(4))) unsigned int uv4;

#define MFMA16(a, b, c) __builtin_amdgcn_mfma_f32_16x16x32_bf16((a), (b), (c), 0, 0, 0)
#define MFMA32(a, b, c) __builtin_amdgcn_mfma_f32_32x32x16_bf16((a), (b), (c), 0, 0, 0)
#define LOG2E 1.4426950408889634f
#define SCALE 0.03125f  // 1/sqrt(1024)

__device__ __forceinline__ u16 f2bf(float f) {
  union { float f; uint32_t u; } cv; cv.f = f;
  uint32_t u = cv.u;
  uint32_t r = (u + 0x7fffu + ((u >> 16) & 1u)) >> 16;  // RTNE
  return (u16)r;
}

__device__ __forceinline__ unsigned cvtpk(float lo, float hi) {
  unsigned r;
  asm("v_cvt_pk_bf16_f32 %0, %1, %2" : "=v"(r) : "v"(lo), "v"(hi));
  return r;
}

__device__ __forceinline__ float m3(float a, float b, float c) {
  return fmaxf(fmaxf(a, b), c);
}

// async global->LDS, 16B per lane; LDS dest = wave-uniform base + lane*16
__device__ __forceinline__ void gld(const void* g, void* l) {
  __builtin_amdgcn_global_load_lds(
      (const __attribute__((address_space(1))) void*)g,
      (__attribute__((address_space(3))) void*)l, 16, 0, 0);
}

// swizzled LDS tile access: tile rows of 64 u16 (128B), 16B chunks XOR'd by row&7.
// LDS position (row, c^ (row&7)) holds element (row, c); staging pre-swizzles the
// GLOBAL source address so linear gload_lds writes land accordingly (rule #21).
__device__ __forceinline__ const short8* tile8(const u16* base, int row, int c) {
  return (const short8*)(base + row * 64 + (((c) ^ (row & 7)) << 3));
}

// ---------------- fp32 -> bf16 conversion ----------------
__global__ void cvt_kernel(const float* __restrict__ src, u16* __restrict__ dst, int n8) {
  int i = blockIdx.x * blockDim.x + threadIdx.x;
  int stride = gridDim.x * blockDim.x;
  for (; i < n8; i += stride) {
    const f32x4* s = (const f32x4*)src + (size_t)i * 2;
    f32x4 a = s[0], b = s[1];
    short8 o;
    o[0] = (short)f2bf(a[0]); o[1] = (short)f2bf(a[1]);
    o[2] = (short)f2bf(a[2]); o[3] = (short)f2bf(a[3]);
    o[4] = (short)f2bf(b[0]); o[5] = (short)f2bf(b[1]);
    o[6] = (short)f2bf(b[2]); o[7] = (short)f2bf(b[3]);
    *((short8*)dst + i) = o;
  }
}

// ---------------- QKV projection GEMM: C = A @ W^T + bias, row-major bf16 out -----
// m97 structure: 128x128 tile, BK=64, global_load_lds(16B) staging, 2 barriers/step.
// Grid 1536 remapped: XCD = bid&7 = m&7 (A-panels L2-resident per XCD), W-panel hot
// across consecutive 8-block windows.
__global__ __launch_bounds__(256) void gemm_qkv(
    const u16* __restrict__ xb,
    const u16* __restrict__ wqb, const u16* __restrict__ wkb, const u16* __restrict__ wvb,
    const float* __restrict__ bq, const float* __restrict__ bk, const float* __restrict__ bv,
    u16* __restrict__ qo, u16* __restrict__ ko, u16* __restrict__ vo) {
  __shared__ __align__(16) u16 sm[2][128 * 64];  // A, B tiles (16KB each)

  const int bid = blockIdx.x;
  const int cx = bid & 7, qq = bid >> 3;
  const int m = ((qq & 7) << 3) + cx;   // 0..63
  const int nz = qq >> 3;               // 0..23
  const int n = nz / 3;
  const int z = nz - n * 3;
  const u16* W = (z == 0) ? wqb : (z == 1) ? wkb : wvb;
  const float* bias = (z == 0) ? bq : (z == 1) ? bk : bv;
  u16* out = (z == 0) ? qo : (z == 1) ? ko : vo;
  const int m0 = m * 128, n0 = n * 128;

  const int t = threadIdx.x;
  const int lane = t & 63;
  const int w = t >> 6;
  const int l15 = lane & 15, l4 = lane >> 4;
  const int mw = (w >> 1) * 64, nw = (w & 1) * 64;

  // staging geometry: chunk = 8 rows x 64 u16 (1KB); wave w owns chunks w*4..w*4+3
  const int srow8 = lane >> 3;                       // row within chunk
  const int ssw = ((lane & 7) ^ srow8) << 3;         // pre-swizzled 16B col (u16 units)
  const u16* aG = xb + (size_t)(m0 + (w * 4) * 8 + srow8) * 1024 + ssw;
  const u16* bG = W + (size_t)(n0 + (w * 4) * 8 + srow8) * 1024 + ssw;
  u16* aL = &sm[0][0] + (w * 4) * 512 + lane * 8;
  u16* bL = &sm[1][0] + (w * 4) * 512 + lane * 8;

  float biasv[4];
#pragma unroll
  for (int nj = 0; nj < 4; nj++) biasv[nj] = bias[n0 + nw + nj * 16 + l15];

  const f32x4 fz = {0.f, 0.f, 0.f, 0.f};
  f32x4 acc[4][4];
#pragma unroll
  for (int i = 0; i < 4; i++)
#pragma unroll
    for (int j = 0; j < 4; j++) acc[i][j] = fz;

  for (int k0 = 0; k0 < 1024; k0 += 64) {
    __syncthreads();  // previous step's frag reads complete
#pragma unroll
    for (int cc = 0; cc < 4; cc++) {
      gld(aG + k0 + (size_t)cc * 8 * 1024, aL + cc * 512);
      gld(bG + k0 + (size_t)cc * 8 * 1024, bL + cc * 512);
    }
    __syncthreads();  // drains vmcnt -> staged data visible
#pragma unroll
    for (int kk = 0; kk < 2; kk++) {
      short8 af[4], bf[4];
#pragma unroll
      for (int mi = 0; mi < 4; mi++) af[mi] = *tile8(&sm[0][0], mw + mi * 16 + l15, kk * 4 + l4);
#pragma unroll
      for (int nj = 0; nj < 4; nj++) bf[nj] = *tile8(&sm[1][0], nw + nj * 16 + l15, kk * 4 + l4);
      __builtin_amdgcn_s_setprio(1);
#pragma unroll
      for (int mi = 0; mi < 4; mi++)
#pragma unroll
        for (int nj = 0; nj < 4; nj++)
          acc[mi][nj] = MFMA16(af[mi], bf[nj], acc[mi][nj]);
      __builtin_amdgcn_s_setprio(0);
    }
  }

  // ---- epilogue: repack via LDS (reuse staging mem), 16B-coalesced stores ----
  __syncthreads();  // all frag reads done before overwrite
  u16* Cs = &sm[0][0] + w * 4096;  // 64x64 u16 per wave, same XOR swizzle
#pragma unroll
  for (int mi = 0; mi < 4; mi++)
#pragma unroll
    for (int nj = 0; nj < 4; nj++)
#pragma unroll
      for (int r = 0; r < 4; r++) {
        const int row = mi * 16 + l4 * 4 + r;
        const int col = nj * 16 + l15;
        Cs[row * 64 + (((col >> 3) ^ (row & 7)) << 3) + (col & 7)] =
            f2bf(acc[mi][nj][r] + biasv[nj]);
      }
#pragma unroll
  for (int i = 0; i < 8; i++) {
    const int row = i * 8 + (lane >> 3);
    short8 vv = *tile8(Cs, row, lane & 7);
    *(short8*)(out + (size_t)(m0 + mw + row) * 1024 + n0 + nw + (lane & 7) * 8) = vv;
  }
}

// ---------------- per-group transpose of V: [2048][64] -> [64][2048] ----------------
__global__ void transpose_v(const u16* __restrict__ v, u16* __restrict__ vt) {
  __shared__ u16 tile[64][72];
  const int g = blockIdx.y, kv0 = blockIdx.x * 64;
  const size_t gb = (size_t)g * 131072;
  const int t = threadIdx.x;
  const int r = t >> 3, c = (t & 7) * 8;
  const u16* src = v + gb + (size_t)kv0 * 64;
#pragma unroll
  for (int rr = 0; rr < 2; rr++) {
    short8 d = *(const short8*)(src + (size_t)(r + rr * 32) * 64 + c);
#pragma unroll
    for (int j = 0; j < 8; j++) tile[r + rr * 32][c + j] = (u16)d[j];
  }
  __syncthreads();
  u16* dst = vt + gb + kv0;
#pragma unroll
  for (int rr = 0; rr < 2; rr++) {
    int h = r + rr * 32;
    short8 o;
#pragma unroll
    for (int j = 0; j < 8; j++) o[j] = (short)tile[c + j][h];
    *(short8*)(dst + (size_t)h * 2048 + c) = o;
  }
}

// ---------------- flash attention: LDS-staged K/V^T, swapped-QK^T 32x32 ----------------
// 64 groups x (S=2048, hd=64). Block = 4 waves x 64 q-rows = 256 q-rows; grid 512.
// Per KV-64 tile: stage K[64][64] + VT[64][64] once per BLOCK (gload_lds, dbuf,
// 1 barrier/tile); each wave: 16 ds_read_b128, 32 MFMA32, in-register softmax.

__device__ __forceinline__ void qblock(f32x16& s, float& m, float& lsum,
                                       f32x16& o0, f32x16& o1,
                                       const short8* vf, int hi) {
  float c0 = m3(s[0], s[1], s[2]);
  float c1 = m3(s[3], s[4], s[5]);
  float c2 = m3(s[6], s[7], s[8]);
  float c3 = m3(s[9], s[10], s[11]);
  float c4 = m3(s[12], s[13], s[14]);
  float cm = fmaxf(m3(m3(c0, c1, c2), c3, c4), s[15]);
  cm = fmaxf(cm, __shfl_xor(cm, 32));
  cm *= SCALE;
  if (!__all(cm - m <= 8.0f)) {  // defer-max (T13)
    float mnew = fmaxf(m, cm);
    float alpha = __builtin_amdgcn_exp2f((m - mnew) * LOG2E);
    lsum *= alpha;
#pragma unroll
    for (int r = 0; r < 16; r++) {
      float ar = __shfl(alpha, (r & 3) + 8 * (r >> 2) + 4 * hi);
      o0[r] *= ar; o1[r] *= ar;
    }
    m = mnew;
  }
  const float kc = SCALE * LOG2E;
  const float ml = m * LOG2E;
  float p[16];
  float ps = 0.f;
#pragma unroll
  for (int i = 0; i < 16; i++) {
    p[i] = __builtin_amdgcn_exp2f(s[i] * kc - ml);
    ps += p[i];
  }
  lsum += ps;

  short8 pa0, pa1;
  {
    unsigned a0 = cvtpk(p[0], p[1]);
    unsigned a1 = cvtpk(p[2], p[3]);
    unsigned b0 = cvtpk(p[4], p[5]);
    unsigned b1 = cvtpk(p[6], p[7]);
    uv2 r0 = __builtin_amdgcn_permlane32_swap(a0, b0, false, false);
    uv2 r1 = __builtin_amdgcn_permlane32_swap(a1, b1, false, false);
    union { uv4 u; short8 s8; } cc;
    cc.u[0] = r0[0]; cc.u[1] = r1[0]; cc.u[2] = r0[1]; cc.u[3] = r1[1];
    pa0 = cc.s8;
  }
  {
    unsigned a0 = cvtpk(p[8], p[9]);
    unsigned a1 = cvtpk(p[10], p[11]);
    unsigned b0 = cvtpk(p[12], p[13]);
    unsigned b1 = cvtpk(p[14], p[15]);
    uv2 r0 = __builtin_amdgcn_permlane32_swap(a0, b0, false, false);
    uv2 r1 = __builtin_amdgcn_permlane32_swap(a1, b1, false, false);
    union { uv4 u; short8 s8; } cc;
    cc.u[0] = r0[0]; cc.u[1] = r1[0]; cc.u[2] = r0[1]; cc.u[3] = r1[1];
    pa1 = cc.s8;
  }
  __builtin_amdgcn_s_setprio(1);
  o0 = MFMA32(pa0, vf[0], o0);
  o0 = MFMA32(pa1, vf[1], o0);
  o1 = MFMA32(pa0, vf[2], o1);
  o1 = MFMA32(pa1, vf[3], o1);
  __builtin_amdgcn_s_setprio(0);
}

__global__ __launch_bounds__(256, 2) void attn_kernel(const u16* __restrict__ q,
                                                      const u16* __restrict__ k,
                                                      const u16* __restrict__ vt,
                                                      float* __restrict__ out) {
  __shared__ __align__(16) u16 Ks[2][64 * 64];
  __shared__ __align__(16) u16 Vs[2][64 * 64];
  const int t = threadIdx.x, lane = t & 63, w = t >> 6;
  const int l31 = lane & 31, hi = lane >> 5;
  const int bid = blockIdx.x;
  const int cxcd = bid & 7, qq = bid >> 3;
  const int g = ((qq >> 3) << 3) + cxcd;  // group; g&7 = XCD
  const int qt = qq & 7;
  const size_t gb = (size_t)g * 131072;
  const int q0 = qt * 256 + w * 64;

  // Q fragments (B-operand of S^T = K Q^T): lane holds Q[q0(+32)+l31][ks*16+hi*8+j]
  const u16* qp = q + gb + (size_t)(q0 + l31) * 64 + hi * 8;
  short8 qfA[4], qfB[4];
#pragma unroll
  for (int ks = 0; ks < 4; ks++) {
    qfA[ks] = *(const short8*)(qp + ks * 16);
    qfB[ks] = *(const short8*)(qp + 32 * 64 + ks * 16);
  }

  // staging pointers: wave w owns chunks w*2, w*2+1 of each 16-chunk... (8 chunks)
  const int srow8 = lane >> 3;
  const int ssw = ((lane & 7) ^ srow8) << 3;  // pre-swizzled source col (u16)
  const u16* kG = k + gb + (size_t)((w * 2) * 8 + srow8) * 64 + ssw;   // + kv0*64
  const u16* vG = vt + gb + (size_t)((w * 2) * 8 + srow8) * 2048 + ssw;  // + kv0
  u16* kL0 = &Ks[0][0] + (w * 2) * 512 + lane * 8;
  u16* vL0 = &Vs[0][0] + (w * 2) * 512 + lane * 8;

  f32x16 oA0, oA1, oB0, oB1;
#pragma unroll
  for (int i = 0; i < 16; i++) { oA0[i] = 0.f; oA1[i] = 0.f; oB0[i] = 0.f; oB1[i] = 0.f; }
  float mA = -1e30f, lA = 0.f, mB = -1e30f, lB = 0.f;

  // prologue: stage tile 0 into buffer 0
#pragma unroll
  for (int cc = 0; cc < 2; cc++) {
    gld(kG + (size_t)cc * 8 * 64, kL0 + cc * 512);
    gld(vG + (size_t)cc * 8 * 2048, vL0 + cc * 512);
  }
  __syncthreads();

  int cur = 0;
  for (int tt = 0; tt < 32; ++tt) {
    if (tt < 31) {
      const int kvn = (tt + 1) * 64;
      u16* kL = &Ks[cur ^ 1][0] + (w * 2) * 512 + lane * 8;
      u16* vL = &Vs[cur ^ 1][0] + (w * 2) * 512 + lane * 8;
#pragma unroll
      for (int cc = 0; cc < 2; cc++) {
        gld(kG + (size_t)kvn * 64 + (size_t)cc * 8 * 64, kL + cc * 512);
        gld(vG + (size_t)kvn + (size_t)cc * 8 * 2048, vL + cc * 512);
      }
    }
    const u16* Kb = &Ks[cur][0];
    const u16* Vb = &Vs[cur][0];
#pragma unroll
    for (int b = 0; b < 2; b++) {
      f32x16 sA, sB;
#pragma unroll
      for (int i = 0; i < 16; i++) { sA[i] = 0.f; sB[i] = 0.f; }
      __builtin_amdgcn_s_setprio(1);
#pragma unroll
      for (int ks = 0; ks < 4; ks++) {
        short8 kf = *tile8(Kb, b * 32 + l31, (ks << 1) | hi);
        sA = MFMA32(kf, qfA[ks], sA);
        sB = MFMA32(kf, qfB[ks], sB);
      }
      __builtin_amdgcn_s_setprio(0);
      short8 vf[4];
#pragma unroll
      for (int h = 0; h < 2; h++)
#pragma unroll
        for (int ksp = 0; ksp < 2; ksp++)
          vf[h * 2 + ksp] = *tile8(Vb, h * 32 + l31, (b << 2) | (ksp << 1) | hi);
      qblock(sA, mA, lA, oA0, oA1, vf, hi);
      qblock(sB, mB, lB, oB0, oB1, vf, hi);
    }
    __syncthreads();  // drains staged loads; all waves done reading cur
    cur ^= 1;
  }

  float ltA = lA + __shfl_xor(lA, 32);
  float ltB = lB + __shfl_xor(lB, 32);
  float invA = 1.0f / ltA, invB = 1.0f / ltB;
  float* obA = out + gb + (size_t)q0 * 64;
  float* obB = obA + 32 * 64;
#pragma unroll
  for (int r = 0; r < 16; r++) {
    int qr = (r & 3) + 8 * (r >> 2) + 4 * hi;
    float irA = __shfl(invA, qr);
    float irB = __shfl(invB, qr);
    obA[(size_t)qr * 64 + l31] = oA0[r] * irA;
    obA[(size_t)qr * 64 + 32 + l31] = oA1[r] * irA;
    obB[(size_t)qr * 64 + l31] = oB0[r] * irB;
    obB[(size_t)qr * 64 + 32 + l31] = oB1[r] * irB;
  }
}

// ---------------- host launch ----------------
extern "C" void kernel_launch(void* const* d_in, const int* in_sizes, int n_in,
                              void* d_out, int out_size, void* d_ws, size_t ws_size,
                              hipStream_t stream) {
  const float* x  = (const float*)d_in[0];
  const float* Wq = (const float*)d_in[1];
  const float* bq = (const float*)d_in[2];
  const float* Wk = (const float*)d_in[3];
  const float* bk = (const float*)d_in[4];
  const float* Wv = (const float*)d_in[5];
  const float* bv = (const float*)d_in[6];
  float* out = (float*)d_out;

  const size_t NX = 8388608;   // 4*2048*1024
  const size_t NW = 1048576;   // 1024*1024
  u16* ws = (u16*)d_ws;
  u16* xb  = ws;
  u16* wqb = xb + NX;
  u16* wkb = wqb + NW;
  u16* wvb = wkb + NW;
  u16* qb  = wvb + NW;   // Q row-major [64][2048][64]
  u16* kb  = qb + NX;    // K row-major
  u16* vb  = kb + NX;    // V row-major
  u16* vtb = vb + NX;    // V^T per group [64][2048]

  cvt_kernel<<<4096, 256, 0, stream>>>(x, xb, (int)(NX / 8));
  cvt_kernel<<<512, 256, 0, stream>>>(Wq, wqb, (int)(NW / 8));
  cvt_kernel<<<512, 256, 0, stream>>>(Wk, wkb, (int)(NW / 8));
  cvt_kernel<<<512, 256, 0, stream>>>(Wv, wvb, (int)(NW / 8));

  gemm_qkv<<<1536, 256, 0, stream>>>(xb, wqb, wkb, wvb, bq, bk, bv, qb, kb, vb);

  transpose_v<<<dim3(32, 64), 256, 0, stream>>>(vb, vtb);

  attn_kernel<<<512, 256, 0, stream>>>(qb, kb, vtb, out);
}